// Round 18
// baseline (237.929 us; speedup 1.0000x reference)
//
#include <hip/hip_runtime.h>
#include <hip/hip_bf16.h>
#include <stdint.h>

// ---------------- types / helpers ----------------
typedef __attribute__((ext_vector_type(8))) short  short8;   // 8 bf16 (4 VGPR)
typedef __attribute__((ext_vector_type(4))) float  f32x4;
typedef __attribute__((ext_vector_type(4))) unsigned int uint4v;
typedef __attribute__((ext_vector_type(4))) unsigned short ushort4v;

#define MFMA16(a,b,c) __builtin_amdgcn_mfma_f32_16x16x32_bf16((a),(b),(c),0,0,0)

#define AS1 __attribute__((address_space(1)))
#define AS3 __attribute__((address_space(3)))
static __device__ __forceinline__ void gload16(void* lds, const void* g) {
  __builtin_amdgcn_global_load_lds((AS1 const void*)g, (AS3 void*)lds, 16, 0, 0);
}

static __device__ __forceinline__ unsigned short f2bf(float x) {  // RNE, finite inputs
  unsigned int u = __float_as_uint(x);
  u += 0x7fffu + ((u >> 16) & 1u);
  return (unsigned short)(u >> 16);
}
static __device__ __forceinline__ unsigned int pkbf(float a, float b) {  // RNE pack (lo=a, hi=b)
  unsigned int u;
  asm("v_cvt_pk_bf16_f32 %0, %1, %2" : "=v"(u) : "v"(a), "v"(b));
  return u;
}

// problem constants
#define HDS   12
#define DD    128
#define DIMK  1536
#define NIN   4608      // 3*1536
#define LV    1920
#define LT    128
#define LL    2048
#define BB    2
#define MV    3840      // B*LV
#define MT    256       // B*LT
#define MTOT  4096
// q pre-scale: 1/sqrt(128) * log2(e)  (logits arrive ready for 2^x)
#define QSC   (0.08838834764831845f * 1.4426950408889634f)

// ---------------- prep: W (K x N f32) -> W^T (N x K) bf16, 2 weights batched ----------------
__global__ __launch_bounds__(256) void transpose_cast2(const float* __restrict__ W0,
                                                       unsigned short* __restrict__ T0,
                                                       const float* __restrict__ W1,
                                                       unsigned short* __restrict__ T1,
                                                       int K, int N) {
  __shared__ float tile[32][33];
  const float* W = blockIdx.z ? W1 : W0;
  unsigned short* T = blockIdx.z ? T1 : T0;
  const int tx = threadIdx.x & 31, ty = threadIdx.x >> 5;  // 32 x 8
  const int k0 = blockIdx.y * 32, n0 = blockIdx.x * 32;
#pragma unroll
  for (int i = 0; i < 32; i += 8)
    tile[ty + i][tx] = W[(size_t)(k0 + ty + i) * N + n0 + tx];
  __syncthreads();
#pragma unroll
  for (int i = 0; i < 32; i += 8)
    T[(size_t)(n0 + ty + i) * K + k0 + tx] = f2bf(tile[tx][ty + i]);
}

// ---------------- fused QKV GEMM (vid+txt, f32 X in) + bias + RMSNorm + pack ----------------
// BM=256 x BN=128, 512 thr, reg-staged dbuf single-barrier (R15-proven schedule).
// A loaded as f32 and converted in-register (v_cvt_pk_bf16_f32, RNE == f2bf).
// V-blocks (s==2) transpose their tile through LDS and write VT (bh, D, L) directly.
__global__ __launch_bounds__(512) void gemm_qkv(
    const float* __restrict__ vidf, const float* __restrict__ txtf,
    const unsigned short* __restrict__ WvH, const unsigned short* __restrict__ WtH,
    const float* __restrict__ bias_v, const float* __restrict__ bias_t,
    const float* __restrict__ nq_v, const float* __restrict__ nk_v,
    const float* __restrict__ nq_t, const float* __restrict__ nk_t,
    unsigned short* __restrict__ qb, unsigned short* __restrict__ kb,
    unsigned short* __restrict__ vt) {
  __shared__ __align__(16) char smem[51200];
  uint4v* sA = (uint4v*)smem;                         // 32KB: 2 halves x 1024 slots
  uint4v* sB = (uint4v*)(smem + 32768);               // 16KB: 2 halves x 512 slots
  float*  rowsq = (float*)(smem + 49152);             // [2][256]
  unsigned short* stg = (unsigned short*)smem;        // V transpose staging [128][137] (35KB)

  const int t = threadIdx.x;
  const int lane = t & 63;
  const int w = t >> 6;
  const int wm = w >> 1, wn = w & 1;
  const int lr = lane & 15, lg = lane >> 4;
  // XCD decode: bid in [0,576), 72 per XCD, 2 M-tiles per XCD
  const int bid = blockIdx.x;
  const int xcd = bid & 7, ii = bid >> 3;          // ii in [0,72)
  const int mt = xcd * 2 + (ii & 1), nt = ii >> 1; // mt in [0,16), nt in [0,36)
  const int m0 = mt * 256, n0 = nt * 128;
  const bool istxt = (m0 >= MV);                   // m-tile 15 = txt rows
  const unsigned short* WThi = istxt ? WtH : WvH;
  const float* bias = istxt ? bias_t : bias_v;
  const int Lmod = istxt ? LT : LV;
  const int loff = istxt ? LV : 0;
  const int mbase = istxt ? MV : 0;
  const float* Xf = (istxt ? txtf : vidf) + (size_t)(m0 - mbase) * DIMK;  // region-local

  f32x4 acc[4][4];
#pragma unroll
  for (int mi = 0; mi < 4; ++mi)
#pragma unroll
    for (int ni = 0; ni < 4; ++ni) acc[mi][ni] = (f32x4){0.f, 0.f, 0.f, 0.f};

  // ---- mainloop: A from f32 (cvt in-register), B from bf16 ----
  {
    const int ra = t >> 1, ca = (t & 1) * 2;   // A: 2 slots/thread
    const int rb = t >> 2, cb = t & 3;         // B: 1 slot/thread
    const size_t arowf = (size_t)ra * DIMK + ca * 8;           // f32 elems
    const size_t brow  = (size_t)(n0 + rb) * DIMK + cb * 8;    // bf16 elems
    const int sa0 = ca * 256 + ra, sa1 = (ca + 1) * 256 + ra;
    const int sb0 = cb * 128 + rb;
    const int fA = lg * 256 + wm * 64 + lr;
    const int fB = lg * 128 + wn * 64 + lr;

    f32x4 fa0 = *(const f32x4*)(Xf + arowf);
    f32x4 fa1 = *(const f32x4*)(Xf + arowf + 4);
    f32x4 fa2 = *(const f32x4*)(Xf + arowf + 8);
    f32x4 fa3 = *(const f32x4*)(Xf + arowf + 12);
    uint4v vb0 = *(const uint4v*)(WThi + brow);

    int cur = 0;
    for (int k0 = 0; k0 < DIMK; k0 += 32) {
      const int ha = cur * 1024, hb = cur * 512;
      uint4v va0 = (uint4v){pkbf(fa0[0], fa0[1]), pkbf(fa0[2], fa0[3]),
                            pkbf(fa1[0], fa1[1]), pkbf(fa1[2], fa1[3])};
      uint4v va1 = (uint4v){pkbf(fa2[0], fa2[1]), pkbf(fa2[2], fa2[3]),
                            pkbf(fa3[0], fa3[1]), pkbf(fa3[2], fa3[3])};
      sA[ha + sa0] = va0; sA[ha + sa1] = va1;
      sB[hb + sb0] = vb0;
      if (k0 + 32 < DIMK) {   // next tile's loads fly across the barrier
        fa0 = *(const f32x4*)(Xf + arowf + k0 + 32);
        fa1 = *(const f32x4*)(Xf + arowf + k0 + 36);
        fa2 = *(const f32x4*)(Xf + arowf + k0 + 40);
        fa3 = *(const f32x4*)(Xf + arowf + k0 + 44);
        vb0 = *(const uint4v*)(WThi + brow + k0 + 32);
      }
      __syncthreads();   // tile k visible; WAR for buf[cur^1]
      short8 ah[4], bh[4];
#pragma unroll
      for (int i = 0; i < 4; ++i) {
        ah[i] = *(const short8*)&sA[ha + fA + i * 16];
        bh[i] = *(const short8*)&sB[hb + fB + i * 16];
      }
#pragma unroll
      for (int mi = 0; mi < 4; ++mi)
#pragma unroll
        for (int ni = 0; ni < 4; ++ni)
          acc[mi][ni] = MFMA16(ah[mi], bh[ni], acc[mi][ni]);
      cur ^= 1;
    }
  }

  const int s  = n0 / DIMK;              // 0=q 1=k 2=v (uniform per block)
  const int hh = (n0 % DIMK) / DD;
#pragma unroll
  for (int ni = 0; ni < 4; ++ni) {
    float bv = bias[n0 + wn * 64 + ni * 16 + lr];
#pragma unroll
    for (int mi = 0; mi < 4; ++mi)
#pragma unroll
      for (int r = 0; r < 4; ++r) acc[mi][ni][r] += bv;
  }

  if (s == 2) {
    // ---- V epilogue: transpose 256x128 tile through LDS, write VT (bh, D, L) ----
    const int dcol = wn * 64;
#pragma unroll
    for (int h = 0; h < 2; ++h) {
      __syncthreads();   // smem free (mainloop done / prev half consumed)
      if ((wm >> 1) == h) {   // waves wm = 2h, 2h+1 own rows h*128..h*128+127
#pragma unroll
        for (int mi = 0; mi < 4; ++mi)
#pragma unroll
          for (int r = 0; r < 4; ++r) {
            int lloc = (wm & 1) * 64 + mi * 16 + lg * 4 + r;   // 0..127
#pragma unroll
            for (int ni = 0; ni < 4; ++ni)
              stg[lloc * 137 + dcol + ni * 16 + lr] = f2bf(acc[mi][ni][r]);
          }
      }
      __syncthreads();
      // read transposed + coalesced global write: 16 lanes cover 128 l; 4 passes over d
      const int lc = t & 15, dd0 = t >> 4;          // dd0 in [0,32)
      int gr = m0 + h * 128 + lc * 8 - mbase;       // region-local row of 8-chunk
      int bidx = (gr >= Lmod) ? 1 : 0;
      int l = loff + gr - bidx * Lmod;
      size_t vbase = (size_t)(bidx * HDS + hh) * DD * LL;
#pragma unroll
      for (int p = 0; p < 4; ++p) {
        int dd = p * 32 + dd0;
        short8 vv;
#pragma unroll
        for (int j = 0; j < 8; ++j)
          vv[j] = (short)stg[(lc * 8 + j) * 137 + dd];
        *(short8*)(vt + vbase + (size_t)dd * LL + l) = vv;
      }
    }
    return;
  }

  // ---- q/k: RMSNorm over the 128 cols of this tile (= head dim) ----
  __syncthreads();
#pragma unroll
  for (int mi = 0; mi < 4; ++mi)
#pragma unroll
    for (int r = 0; r < 4; ++r) {
      float p = 0.f;
#pragma unroll
      for (int ni = 0; ni < 4; ++ni) p += acc[mi][ni][r] * acc[mi][ni][r];
      p += __shfl_xor(p, 1); p += __shfl_xor(p, 2);
      p += __shfl_xor(p, 4); p += __shfl_xor(p, 8);
      if (lr == 0) rowsq[wn * 256 + wm * 64 + mi * 16 + lg * 4 + r] = p;
    }
  __syncthreads();
  {
    const float* nw = (s == 0) ? (istxt ? nq_t : nq_v) : (istxt ? nk_t : nk_v);
    const float post = (s == 0) ? QSC : 1.0f;   // fold softmax scale*log2e into q
    float nwv[4];
#pragma unroll
    for (int ni = 0; ni < 4; ++ni) nwv[ni] = nw[wn * 64 + ni * 16 + lr] * post;
#pragma unroll
    for (int mi = 0; mi < 4; ++mi)
#pragma unroll
      for (int r = 0; r < 4; ++r) {
        int row = wm * 64 + mi * 16 + lg * 4 + r;
        float a = (rowsq[row] + rowsq[256 + row]) * (1.f / 128.f) + 1e-6f;
        float x = rsqrtf(a);
        x = x * (1.5f - 0.5f * a * x * x);   // Newton refine -> ~f32 exact
#pragma unroll
        for (int ni = 0; ni < 4; ++ni) acc[mi][ni][r] *= x * nwv[ni];
      }
  }
  unsigned short* dst = (s == 0) ? qb : kb;
#pragma unroll
  for (int mi = 0; mi < 4; ++mi)
#pragma unroll
    for (int r = 0; r < 4; ++r) {
      int mrow = m0 + wm * 64 + mi * 16 + lg * 4 + r - mbase;  // region-local
      int bidx = (mrow >= Lmod) ? 1 : 0;
      int l = loff + mrow - bidx * Lmod;
      size_t rb2 = ((size_t)(bidx * HDS + hh) * LL + l) * DD;
#pragma unroll
      for (int ni = 0; ni < 4; ++ni) {
        int d = wn * 64 + ni * 16 + lr;
        dst[rb2 + d] = f2bf(acc[mi][ni][r]);
      }
    }
}

// ---------------- attention v8 (R15-proven): 4 waves/block, VALU-lean single pass ----------------
__global__ __launch_bounds__(256) void attn_kernel(
    const unsigned short* __restrict__ qb, const unsigned short* __restrict__ kb,
    const unsigned short* __restrict__ vt,
    unsigned short* __restrict__ aohi) {
  const int t = threadIdx.x;
  const int lane = t & 63, w = t >> 6;
  const int lr = lane & 15, lg = lane >> 4;
  // bid in [0,768): xcd = bid&7 owns heads [xcd*3, xcd*3+3)
  const int bid = blockIdx.x;
  const int xcd = bid & 7, ii = bid >> 3;        // ii in [0,96)
  const int bh = xcd * 3 + (ii >> 5);            // [0,24)
  const int qt = ii & 31;                        // [0,32)
  const int q0 = (qt * 4 + w) * 16;
  const size_t base = (size_t)bh * LL * DD;

  __shared__ __align__(16) unsigned short Kbuf[2][32 * 128];  // 8192B/buf, swz (row&7)<<4
  __shared__ __align__(16) unsigned short Vbuf[2][128 * 32];  // 8192B/buf, swz (row&3)<<4
  __shared__ __align__(16) unsigned short P[4][16 * 40];      // per-wave, 1280B, stride 80B

  const char* kglob = (const char*)(kb + base);
  const char* vglob = (const char*)(vt + base);

  // ---- staging constants (lane-invariant parts hoisted) ----
  const int  srcK  = (t * 16) ^ (((t >> 4) & 7) << 4);                 // inverse K swizzle
  const size_t vs0 = (size_t)(t >> 2) * (LL * 2) +
                     (((t & 3) ^ ((t >> 2) & 3)) << 4);                // inverse V swizzle
  const size_t vs1 = vs0 + (size_t)64 * (LL * 2);
  char* kd0 = (char*)Kbuf + w * 1024;
  char* kd1 = kd0 + 4096;
  char* vd0 = (char*)Vbuf + w * 1024;
  char* vd1 = vd0 + 4096;

  // ---- read addresses (lane-constant) ----
  int akr[2][4];
#pragma unroll
  for (int h = 0; h < 2; ++h) {
    const int rr = 2 * lr + h;
#pragma unroll
    for (int ks = 0; ks < 4; ++ks)
      akr[h][ks] = rr * 256 + ((ks * 64 + lg * 16) ^ ((rr & 7) << 4));
  }
  const int av0 = lr * 64 + ((lg ^ (lr & 3)) << 4);
  char* pwr = (char*)P + w * 1280 + lg * 320 + lr * 4;
  const char* prd = (const char*)P + w * 1280 + lr * 80 + lg * 16;
  const char* KBp = (const char*)Kbuf;
  const char* VBp = (const char*)Vbuf;

  // ---- Q fragments (pre-scaled in gemm_qkv) ----
  short8 qf[4];
#pragma unroll
  for (int ks = 0; ks < 4; ++ks)
    qf[ks] = *(const short8*)(qb + base + (size_t)(q0 + lr) * DD + ks * 32 + lg * 8);

  f32x4 o[8];
#pragma unroll
  for (int i = 0; i < 8; ++i) o[i] = (f32x4){0.f, 0.f, 0.f, 0.f};
  float Z[4] = {0.f, 0.f, 0.f, 0.f};

  const char* gkp = kglob;
  const char* gvp = vglob;
  // prologue: stage tile 0 into buf 0
  gload16(kd0, gkp + srcK);
  gload16(kd1, gkp + 4096 + srcK);
  gload16(vd0, gvp + vs0);
  gload16(vd1, gvp + vs1);
  __syncthreads();

#pragma unroll 2
  for (int kt = 0; kt < LL / 32; ++kt) {
    const int cur = kt & 1;
    const int cb = cur * 8192, nb = (cur ^ 1) * 8192;
    if (kt + 1 < LL / 32) {   // stage next tile; loads fly until end-of-iter barrier
      gload16(kd0 + nb, gkp + 8192 + srcK);
      gload16(kd1 + nb, gkp + 8192 + 4096 + srcK);
      gload16(vd0 + nb, gvp + 64 + vs0);
      gload16(vd1 + nb, gvp + 64 + vs1);
    }
    f32x4 s0a = (f32x4){0.f, 0.f, 0.f, 0.f}, s0b = (f32x4){0.f, 0.f, 0.f, 0.f};
    f32x4 s1a = (f32x4){0.f, 0.f, 0.f, 0.f}, s1b = (f32x4){0.f, 0.f, 0.f, 0.f};
#pragma unroll
    for (int ks = 0; ks < 4; ++ks) {
      short8 k0f = *(const short8*)(KBp + cb + akr[0][ks]);
      short8 k1f = *(const short8*)(KBp + cb + akr[1][ks]);
      if (ks < 2) { s0a = MFMA16(qf[ks], k0f, s0a); s1a = MFMA16(qf[ks], k1f, s1a); }
      else        { s0b = MFMA16(qf[ks], k0f, s0b); s1b = MFMA16(qf[ks], k1f, s1b); }
    }
#pragma unroll
    for (int r = 0; r < 4; ++r) {
      float p0, p1;
      float sa = s0a[r] + s0b[r];   // logit*log2e (pre-scaled q)
      float sb = s1a[r] + s1b[r];
      asm("v_exp_f32 %0, %1" : "=v"(p0) : "v"(sa));   // 2^x == exp(s)
      asm("v_exp_f32 %0, %1" : "=v"(p1) : "v"(sb));
      Z[r] += p0 + p1;
      unsigned int u;
      asm("v_cvt_pk_bf16_f32 %0, %1, %2" : "=v"(u) : "v"(p0), "v"(p1));
      *(unsigned int*)(pwr + r * 80) = u;   // cols 2lr, 2lr+1 (kv-interleaved)
    }
    // same-wave P write -> read: compiler-ordered via lgkmcnt (no barrier needed)
    short8 pa = *(const short8*)prd;
#pragma unroll
    for (int df = 0; df < 8; ++df) {
      short8 vf = *(const short8*)(VBp + cb + df * 1024 + av0);
      o[df] = MFMA16(pa, vf, o[df]);
    }
    __syncthreads();   // drains vmcnt: staged kt+1 visible; orders reads before next stage
    gkp += 8192; gvp += 64;
  }

  float invZ[4];
#pragma unroll
  for (int r = 0; r < 4; ++r) {
    Z[r] += __shfl_xor(Z[r], 1); Z[r] += __shfl_xor(Z[r], 2);
    Z[r] += __shfl_xor(Z[r], 4); Z[r] += __shfl_xor(Z[r], 8);
    invZ[r] = 1.0f / Z[r];
  }

  const int b = bh / HDS, h = bh % HDS;
#pragma unroll
  for (int df = 0; df < 8; ++df)
#pragma unroll
    for (int r = 0; r < 4; ++r) {
      int l = q0 + lg * 4 + r;
      size_t row = (l < LV) ? ((size_t)b * LV + l) : ((size_t)MV + b * LT + (l - LV));
      int col = h * DD + df * 16 + lr;
      aohi[row * DIMK + col] = f2bf(o[df][r] * invZ[r]);
    }
}

// ---------------- pure-bf16 mainloop, BM=128, 2-deep prefetch (for gemm_out) ----------------
__device__ __forceinline__ void bf16_mainloop128(
    const unsigned short* __restrict__ Ahi, const unsigned short* __restrict__ Bhi,
    int m0, int n0,
    uint4v* __restrict__ sA, uint4v* __restrict__ sB,
    f32x4 (&acc)[4][4]) {
  const int t = threadIdx.x;
  const int lane = t & 63;
  const int w = t >> 6;
  const int wm = w >> 1, wn = w & 1;
  const int lr = lane & 15, lg = lane >> 4;
  const int sr = t >> 1;
  const int sc = (t & 1) * 2;
  const size_t arow = (size_t)(m0 + sr) * DIMK + sc * 8;
  const size_t brow = (size_t)(n0 + sr) * DIMK + sc * 8;
  const int slot0 = sc * 128 + sr, slot1 = (sc + 1) * 128 + sr;
  const int fA = lg * 128 + wm * 64 + lr;
  const int fB = lg * 128 + wn * 64 + lr;

  // set A <- tile 0, set B <- tile 1
  uint4v aA0 = *(const uint4v*)(Ahi + arow);
  uint4v aA1 = *(const uint4v*)(Ahi + arow + 8);
  uint4v bA0 = *(const uint4v*)(Bhi + brow);
  uint4v bA1 = *(const uint4v*)(Bhi + brow + 8);
  uint4v aB0 = *(const uint4v*)(Ahi + arow + 32);
  uint4v aB1 = *(const uint4v*)(Ahi + arow + 40);
  uint4v bB0 = *(const uint4v*)(Bhi + brow + 32);
  uint4v bB1 = *(const uint4v*)(Bhi + brow + 40);

  for (int k0 = 0; k0 < DIMK; k0 += 64) {
    // ---- phase A: tile k0 -> LDS half 0 ----
    sA[slot0] = aA0; sA[slot1] = aA1;
    sB[slot0] = bA0; sB[slot1] = bA1;
    if (k0 + 64 < DIMK) {
      aA0 = *(const uint4v*)(Ahi + arow + k0 + 64);
      aA1 = *(const uint4v*)(Ahi + arow + k0 + 72);
      bA0 = *(const uint4v*)(Bhi + brow + k0 + 64);
      bA1 = *(const uint4v*)(Bhi + brow + k0 + 72);
    }
    __syncthreads();
    {
      short8 ah[4], bh[4];
#pragma unroll
      for (int i = 0; i < 4; ++i) {
        ah[i] = *(const short8*)&sA[fA + i * 16];
        bh[i] = *(const short8*)&sB[fB + i * 16];
      }
#pragma unroll
      for (int mi = 0; mi < 4; ++mi)
#pragma unroll
        for (int ni = 0; ni < 4; ++ni)
          acc[mi][ni] = MFMA16(ah[mi], bh[ni], acc[mi][ni]);
    }
    // ---- phase B: tile k0+32 -> LDS half 1 ----
    sA[512 + slot0] = aB0; sA[512 + slot1] = aB1;
    sB[512 + slot0] = bB0; sB[512 + slot1] = bB1;
    if (k0 + 96 < DIMK) {
      aB0 = *(const uint4v*)(Ahi + arow + k0 + 96);
      aB1 = *(const uint4v*)(Ahi + arow + k0 + 104);
      bB0 = *(const uint4v*)(Bhi + brow + k0 + 96);
      bB1 = *(const uint4v*)(Bhi + brow + k0 + 104);
    }
    __syncthreads();
    {
      short8 ah[4], bh[4];
#pragma unroll
      for (int i = 0; i < 4; ++i) {
        ah[i] = *(const short8*)&sA[512 + fA + i * 16];
        bh[i] = *(const short8*)&sB[512 + fB + i * 16];
      }
#pragma unroll
      for (int mi = 0; mi < 4; ++mi)
#pragma unroll
        for (int ni = 0; ni < 4; ++ni)
          acc[mi][ni] = MFMA16(ah[mi], bh[ni], acc[mi][ni]);
    }
  }
}

// ---------------- fused output GEMM (vid+txt) + bias -> f32 d_out ----------------
__global__ __launch_bounds__(256) void gemm_out(
    const unsigned short* __restrict__ Ahi,
    const unsigned short* __restrict__ WvH, const unsigned short* __restrict__ WtH,
    const float* __restrict__ bias_v, const float* __restrict__ bias_t,
    float* __restrict__ out) {
  __shared__ uint4v sA[1024], sB[1024];   // 32KB (dbuf)
  const int t = threadIdx.x;
  const int lane = t & 63;
  const int w = t >> 6;
  const int wm = w >> 1, wn = w & 1;
  const int lr = lane & 15, lg = lane >> 4;
  // XCD decode: bid in [0,384), 48 per XCD, M-chunk of 4 tiles per XCD
  const int bid = blockIdx.x;
  const int xcd = bid & 7, ii = bid >> 3;          // ii in [0,48)
  const int mt = xcd * 4 + (ii & 3), nt = ii >> 2; // mt in [0,32), nt in [0,12)
  const int m0 = mt * 128, n0 = nt * 128;
  const bool istxt = (m0 >= MV);
  const unsigned short* WThi = istxt ? WtH : WvH;
  const float* bias = istxt ? bias_t : bias_v;

  f32x4 acc[4][4];
#pragma unroll
  for (int mi = 0; mi < 4; ++mi)
#pragma unroll
    for (int ni = 0; ni < 4; ++ni) acc[mi][ni] = (f32x4){0.f, 0.f, 0.f, 0.f};

  bf16_mainloop128(Ahi, WThi, m0, n0, sA, sB, acc);

#pragma unroll
  for (int ni = 0; ni < 4; ++ni) {
    float bv = bias[n0 + wn * 64 + ni * 16 + lr];
#pragma unroll
    for (int mi = 0; mi < 4; ++mi)
#pragma unroll
      for (int r = 0; r < 4; ++r) {
        size_t row = (size_t)(m0 + wm * 64 + mi * 16 + lg * 4 + r);
        out[row * DIMK + n0 + wn * 64 + ni * 16 + lr] = acc[mi][ni][r] + bv;
      }
  }
}

// ---------------- launcher ----------------
extern "C" void kernel_launch(void* const* d_in, const int* in_sizes, int n_in,
                              void* d_out, int out_size, void* d_ws, size_t ws_size,
                              hipStream_t stream) {
  (void)in_sizes; (void)n_in; (void)out_size; (void)ws_size;
  const float* vid      = (const float*)d_in[0];
  const float* txt      = (const float*)d_in[1];
  const float* Wqkv_vid = (const float*)d_in[2];
  const float* bqkv_vid = (const float*)d_in[3];
  const float* Wqkv_txt = (const float*)d_in[4];
  const float* bqkv_txt = (const float*)d_in[5];
  const float* nq_vid   = (const float*)d_in[6];
  const float* nk_vid   = (const float*)d_in[7];
  const float* nq_txt   = (const float*)d_in[8];
  const float* nk_txt   = (const float*)d_in[9];
  const float* Wout_vid = (const float*)d_in[10];
  const float* bout_vid = (const float*)d_in[11];
  const float* Wout_txt = (const float*)d_in[12];
  const float* bout_txt = (const float*)d_in[13];
  float* out = (float*)d_out;

  char* ws = (char*)d_ws;
  size_t off = 0;
  auto alloc = [&](size_t bytes) { char* p = ws + off; off += (bytes + 255) & ~(size_t)255; return p; };

  const size_t SZ_WQKV = (size_t)NIN * DIMK * 2;    // bf16 bytes
  const size_t SZ_WOUT = (size_t)DIMK * DIMK * 2;
  const size_t SZ_QKVB = (size_t)BB * HDS * LL * DD * 2;
  const size_t SZ_AO   = (size_t)MTOT * DIMK * 2;

  unsigned short* WTqvH = (unsigned short*)alloc(SZ_WQKV);
  unsigned short* WTqtH = (unsigned short*)alloc(SZ_WQKV);
  unsigned short* WTovH = (unsigned short*)alloc(SZ_WOUT);
  unsigned short* WTotH = (unsigned short*)alloc(SZ_WOUT);
  unsigned short* QB    = (unsigned short*)alloc(SZ_QKVB);
  unsigned short* KB    = (unsigned short*)alloc(SZ_QKVB);
  unsigned short* VT    = (unsigned short*)alloc(SZ_QKVB);
  unsigned short* AOhi  = (unsigned short*)alloc(SZ_AO);

  transpose_cast2<<<dim3(NIN / 32, DIMK / 32, 2), dim3(256), 0, stream>>>(
      Wqkv_vid, WTqvH, Wqkv_txt, WTqtH, DIMK, NIN);
  transpose_cast2<<<dim3(DIMK / 32, DIMK / 32, 2), dim3(256), 0, stream>>>(
      Wout_vid, WTovH, Wout_txt, WTotH, DIMK, DIMK);
  gemm_qkv<<<dim3(576), dim3(512), 0, stream>>>(
      vid, txt, WTqvH, WTqtH, bqkv_vid, bqkv_txt,
      nq_vid, nk_vid, nq_txt, nk_txt, QB, KB, VT);
  attn_kernel<<<dim3(768), dim3(256), 0, stream>>>(QB, KB, VT, AOhi);
  gemm_out<<<dim3(384), dim3(256), 0, stream>>>(
      AOhi, WTovH, WTotH, bout_vid, bout_txt, out);
}

// Round 19
// 225.581 us; speedup vs baseline: 1.0547x; 1.0547x over previous
//
#include <hip/hip_runtime.h>
#include <hip/hip_bf16.h>
#include <stdint.h>

// ---------------- types / helpers ----------------
typedef __attribute__((ext_vector_type(8))) short  short8;   // 8 bf16 (4 VGPR)
typedef __attribute__((ext_vector_type(4))) float  f32x4;
typedef __attribute__((ext_vector_type(4))) unsigned int uint4v;
typedef __attribute__((ext_vector_type(4))) unsigned short ushort4v;

#define MFMA16(a,b,c) __builtin_amdgcn_mfma_f32_16x16x32_bf16((a),(b),(c),0,0,0)

#define AS1 __attribute__((address_space(1)))
#define AS3 __attribute__((address_space(3)))
static __device__ __forceinline__ void gload16(void* lds, const void* g) {
  __builtin_amdgcn_global_load_lds((AS1 const void*)g, (AS3 void*)lds, 16, 0, 0);
}

static __device__ __forceinline__ unsigned short f2bf(float x) {  // RNE, finite inputs
  unsigned int u = __float_as_uint(x);
  u += 0x7fffu + ((u >> 16) & 1u);
  return (unsigned short)(u >> 16);
}

// problem constants
#define HDS   12
#define DD    128
#define DIMK  1536
#define NIN   4608      // 3*1536
#define LV    1920
#define LT    128
#define LL    2048
#define BB    2
#define MV    3840      // B*LV
#define MT    256       // B*LT
#define MTOT  4096
// q pre-scale: 1/sqrt(128) * log2(e)  (logits arrive ready for 2^x)
#define QSC   (0.08838834764831845f * 1.4426950408889634f)

// ---------------- prep: cast activations to bf16 ----------------
__global__ __launch_bounds__(256) void split_x(const float* __restrict__ vid,
                                               const float* __restrict__ txt,
                                               unsigned short* __restrict__ xhi) {
  size_t i = ((size_t)blockIdx.x * 256 + threadIdx.x) * 4;
  const size_t NV = (size_t)MV * DIMK;
  const float* src = (i < NV) ? (vid + i) : (txt + (i - NV));
  f32x4 v = *(const f32x4*)src;
  ushort4v hv;
#pragma unroll
  for (int j = 0; j < 4; ++j) hv[j] = f2bf(v[j]);
  *(ushort4v*)(xhi + i) = hv;
}

// ---------------- prep: W (K x N f32) -> W^T (N x K) bf16, 2 weights batched ----------------
__global__ __launch_bounds__(256) void transpose_cast2(const float* __restrict__ W0,
                                                       unsigned short* __restrict__ T0,
                                                       const float* __restrict__ W1,
                                                       unsigned short* __restrict__ T1,
                                                       int K, int N) {
  __shared__ float tile[32][33];
  const float* W = blockIdx.z ? W1 : W0;
  unsigned short* T = blockIdx.z ? T1 : T0;
  const int tx = threadIdx.x & 31, ty = threadIdx.x >> 5;  // 32 x 8
  const int k0 = blockIdx.y * 32, n0 = blockIdx.x * 32;
#pragma unroll
  for (int i = 0; i < 32; i += 8)
    tile[ty + i][tx] = W[(size_t)(k0 + ty + i) * N + n0 + tx];
  __syncthreads();
#pragma unroll
  for (int i = 0; i < 32; i += 8)
    T[(size_t)(n0 + ty + i) * K + k0 + tx] = f2bf(tile[tx][ty + i]);
}

// ---------------- prep: V (bh, L, D) -> Vt (bh, D, L) ----------------
__global__ __launch_bounds__(256) void vt_transpose(const unsigned short* __restrict__ v,
                                                    unsigned short* __restrict__ vtb) {
  __shared__ unsigned short tile[32][33];
  const int tx = threadIdx.x & 31, ty = threadIdx.x >> 5;
  const int bh = blockIdx.z;
  const int l0 = blockIdx.x * 32, d0 = blockIdx.y * 32;
  const size_t base = (size_t)bh * LL * DD;
#pragma unroll
  for (int i = 0; i < 32; i += 8)
    tile[ty + i][tx] = v[base + (size_t)(l0 + ty + i) * DD + d0 + tx];
  __syncthreads();
#pragma unroll
  for (int i = 0; i < 32; i += 8)
    vtb[base + (size_t)(d0 + ty + i) * LL + l0 + tx] = tile[tx][ty + i];
}

// ---------------- pure-bf16 mainloop, BM=256 x BN=128, dbuf single-barrier ----------------
__device__ __forceinline__ void bf16_mainloop256(
    const unsigned short* __restrict__ Ahi, const unsigned short* __restrict__ Bhi,
    int m0, int n0,
    uint4v* __restrict__ sA, uint4v* __restrict__ sB,
    f32x4 (&acc)[4][4]) {
  const int t = threadIdx.x;            // 0..511
  const int lane = t & 63;
  const int w = t >> 6;                 // 0..7
  const int wm = w >> 1, wn = w & 1;
  const int lr = lane & 15, lg = lane >> 4;
  const int ra = t >> 1, ca = (t & 1) * 2;   // A: 2 slots/thread (1024 slots/tile)
  const int rb = t >> 2, cb = t & 3;         // B: 1 slot/thread (512 slots/tile)
  const size_t arow = (size_t)(m0 + ra) * DIMK + ca * 8;
  const size_t brow = (size_t)(n0 + rb) * DIMK + cb * 8;
  const int sa0 = ca * 256 + ra, sa1 = (ca + 1) * 256 + ra;
  const int sb0 = cb * 128 + rb;
  const int fA = lg * 256 + wm * 64 + lr;
  const int fB = lg * 128 + wn * 64 + lr;

  uint4v va0 = *(const uint4v*)(Ahi + arow);
  uint4v va1 = *(const uint4v*)(Ahi + arow + 8);
  uint4v vb0 = *(const uint4v*)(Bhi + brow);

  int cur = 0;
  for (int k0 = 0; k0 < DIMK; k0 += 32) {
    const int ha = cur * 1024, hb = cur * 512;
    sA[ha + sa0] = va0; sA[ha + sa1] = va1;
    sB[hb + sb0] = vb0;
    if (k0 + 32 < DIMK) {   // issue next tile's loads; they fly across the barrier
      va0 = *(const uint4v*)(Ahi + arow + k0 + 32);
      va1 = *(const uint4v*)(Ahi + arow + k0 + 40);
      vb0 = *(const uint4v*)(Bhi + brow + k0 + 32);
    }
    __syncthreads();   // tile k visible; WAR for buf[cur^1] (written next iter)
    short8 ah[4], bh[4];
#pragma unroll
    for (int i = 0; i < 4; ++i) {
      ah[i] = *(const short8*)&sA[ha + fA + i * 16];
      bh[i] = *(const short8*)&sB[hb + fB + i * 16];
    }
#pragma unroll
    for (int mi = 0; mi < 4; ++mi)
#pragma unroll
      for (int ni = 0; ni < 4; ++ni)
        acc[mi][ni] = MFMA16(ah[mi], bh[ni], acc[mi][ni]);
    cur ^= 1;
  }
}

// ---------------- fused QKV GEMM (vid+txt) + bias + RMSNorm + pack, BM=256 ----------------
__global__ __launch_bounds__(512) void gemm_qkv(
    const unsigned short* __restrict__ Xhi,
    const unsigned short* __restrict__ WvH, const unsigned short* __restrict__ WtH,
    const float* __restrict__ bias_v, const float* __restrict__ bias_t,
    const float* __restrict__ nq_v, const float* __restrict__ nk_v,
    const float* __restrict__ nq_t, const float* __restrict__ nk_t,
    unsigned short* __restrict__ qb, unsigned short* __restrict__ kb,
    unsigned short* __restrict__ vb) {
  __shared__ uint4v sA[2048], sB[1024];   // 48KB (dbuf)
  __shared__ float rowsq[2][256];
  const int t = threadIdx.x;
  const int lane = t & 63;
  const int w = t >> 6;
  const int wm = w >> 1, wn = w & 1;
  const int lr = lane & 15, lg = lane >> 4;
  // XCD decode: bid in [0,576), 72 per XCD, 2 M-tiles per XCD (A-slab 1.5MB in L2)
  const int bid = blockIdx.x;
  const int xcd = bid & 7, ii = bid >> 3;          // ii in [0,72)
  const int mt = xcd * 2 + (ii & 1), nt = ii >> 1; // mt in [0,16), nt in [0,36)
  const int m0 = mt * 256, n0 = nt * 128;
  const bool istxt = (m0 >= MV);                   // m-tile 15 = txt rows
  const unsigned short* WThi = istxt ? WtH : WvH;
  const float* bias = istxt ? bias_t : bias_v;
  const int Lmod = istxt ? LT : LV;
  const int loff = istxt ? LV : 0;
  const int mbase = istxt ? MV : 0;

  f32x4 acc[4][4];
#pragma unroll
  for (int mi = 0; mi < 4; ++mi)
#pragma unroll
    for (int ni = 0; ni < 4; ++ni) acc[mi][ni] = (f32x4){0.f, 0.f, 0.f, 0.f};

  bf16_mainloop256(Xhi, WThi, m0, n0, sA, sB, acc);

  const int s  = n0 / DIMK;              // 0=q 1=k 2=v (uniform per block)
  const int hh = (n0 % DIMK) / DD;
#pragma unroll
  for (int ni = 0; ni < 4; ++ni) {
    float bv = bias[n0 + wn * 64 + ni * 16 + lr];
#pragma unroll
    for (int mi = 0; mi < 4; ++mi)
#pragma unroll
      for (int r = 0; r < 4; ++r) acc[mi][ni][r] += bv;
  }
  if (s < 2) {  // RMSNorm over the 128 cols of this tile (= head dim)
    __syncthreads();
#pragma unroll
    for (int mi = 0; mi < 4; ++mi)
#pragma unroll
      for (int r = 0; r < 4; ++r) {
        float p = 0.f;
#pragma unroll
        for (int ni = 0; ni < 4; ++ni) p += acc[mi][ni][r] * acc[mi][ni][r];
        p += __shfl_xor(p, 1); p += __shfl_xor(p, 2);
        p += __shfl_xor(p, 4); p += __shfl_xor(p, 8);
        if (lr == 0) rowsq[wn][wm * 64 + mi * 16 + lg * 4 + r] = p;
      }
    __syncthreads();
    const float* nw = (s == 0) ? (istxt ? nq_t : nq_v) : (istxt ? nk_t : nk_v);
    const float post = (s == 0) ? QSC : 1.0f;   // fold softmax scale*log2e into q
    float nwv[4];
#pragma unroll
    for (int ni = 0; ni < 4; ++ni) nwv[ni] = nw[wn * 64 + ni * 16 + lr] * post;
#pragma unroll
    for (int mi = 0; mi < 4; ++mi)
#pragma unroll
      for (int r = 0; r < 4; ++r) {
        int row = wm * 64 + mi * 16 + lg * 4 + r;
        float a = (rowsq[0][row] + rowsq[1][row]) * (1.f / 128.f) + 1e-6f;
        float x = rsqrtf(a);
        x = x * (1.5f - 0.5f * a * x * x);   // Newton refine -> ~f32 exact
#pragma unroll
        for (int ni = 0; ni < 4; ++ni) acc[mi][ni][r] *= x * nwv[ni];
      }
  }
  unsigned short* dst = (s == 0) ? qb : ((s == 1) ? kb : vb);
#pragma unroll
  for (int mi = 0; mi < 4; ++mi)
#pragma unroll
    for (int r = 0; r < 4; ++r) {
      int mrow = m0 + wm * 64 + mi * 16 + lg * 4 + r - mbase;  // region-local
      int bidx = (mrow >= Lmod) ? 1 : 0;
      int l = loff + mrow - bidx * Lmod;
      size_t rb2 = ((size_t)(bidx * HDS + hh) * LL + l) * DD;
#pragma unroll
      for (int ni = 0; ni < 4; ++ni) {
        int d = wn * 64 + ni * 16 + lr;
        dst[rb2 + d] = f2bf(acc[mi][ni][r]);
      }
    }
}

// ---------------- attention v8 (R15-proven): 4 waves/block, VALU-lean single pass ----------------
__global__ __launch_bounds__(256) void attn_kernel(
    const unsigned short* __restrict__ qb, const unsigned short* __restrict__ kb,
    const unsigned short* __restrict__ vt,
    unsigned short* __restrict__ aohi) {
  const int t = threadIdx.x;
  const int lane = t & 63, w = t >> 6;
  const int lr = lane & 15, lg = lane >> 4;
  // bid in [0,768): xcd = bid&7 owns heads [xcd*3, xcd*3+3)
  const int bid = blockIdx.x;
  const int xcd = bid & 7, ii = bid >> 3;        // ii in [0,96)
  const int bh = xcd * 3 + (ii >> 5);            // [0,24)
  const int qt = ii & 31;                        // [0,32)
  const int q0 = (qt * 4 + w) * 16;
  const size_t base = (size_t)bh * LL * DD;

  __shared__ __align__(16) unsigned short Kbuf[2][32 * 128];  // 8192B/buf, swz (row&7)<<4
  __shared__ __align__(16) unsigned short Vbuf[2][128 * 32];  // 8192B/buf, swz (row&3)<<4
  __shared__ __align__(16) unsigned short P[4][16 * 40];      // per-wave, 1280B, stride 80B

  const char* kglob = (const char*)(kb + base);
  const char* vglob = (const char*)(vt + base);

  // ---- staging constants (lane-invariant parts hoisted) ----
  const int  srcK  = (t * 16) ^ (((t >> 4) & 7) << 4);                 // inverse K swizzle
  const size_t vs0 = (size_t)(t >> 2) * (LL * 2) +
                     (((t & 3) ^ ((t >> 2) & 3)) << 4);                // inverse V swizzle
  const size_t vs1 = vs0 + (size_t)64 * (LL * 2);
  char* kd0 = (char*)Kbuf + w * 1024;
  char* kd1 = kd0 + 4096;
  char* vd0 = (char*)Vbuf + w * 1024;
  char* vd1 = vd0 + 4096;

  // ---- read addresses (lane-constant) ----
  int akr[2][4];
#pragma unroll
  for (int h = 0; h < 2; ++h) {
    const int rr = 2 * lr + h;
#pragma unroll
    for (int ks = 0; ks < 4; ++ks)
      akr[h][ks] = rr * 256 + ((ks * 64 + lg * 16) ^ ((rr & 7) << 4));
  }
  const int av0 = lr * 64 + ((lg ^ (lr & 3)) << 4);
  char* pwr = (char*)P + w * 1280 + lg * 320 + lr * 4;
  const char* prd = (const char*)P + w * 1280 + lr * 80 + lg * 16;
  const char* KBp = (const char*)Kbuf;
  const char* VBp = (const char*)Vbuf;

  // ---- Q fragments (pre-scaled in gemm_qkv) ----
  short8 qf[4];
#pragma unroll
  for (int ks = 0; ks < 4; ++ks)
    qf[ks] = *(const short8*)(qb + base + (size_t)(q0 + lr) * DD + ks * 32 + lg * 8);

  f32x4 o[8];
#pragma unroll
  for (int i = 0; i < 8; ++i) o[i] = (f32x4){0.f, 0.f, 0.f, 0.f};
  float Z[4] = {0.f, 0.f, 0.f, 0.f};

  const char* gkp = kglob;
  const char* gvp = vglob;
  // prologue: stage tile 0 into buf 0
  gload16(kd0, gkp + srcK);
  gload16(kd1, gkp + 4096 + srcK);
  gload16(vd0, gvp + vs0);
  gload16(vd1, gvp + vs1);
  __syncthreads();

#pragma unroll 2
  for (int kt = 0; kt < LL / 32; ++kt) {
    const int cur = kt & 1;
    const int cb = cur * 8192, nb = (cur ^ 1) * 8192;
    if (kt + 1 < LL / 32) {   // stage next tile; loads fly until end-of-iter barrier
      gload16(kd0 + nb, gkp + 8192 + srcK);
      gload16(kd1 + nb, gkp + 8192 + 4096 + srcK);
      gload16(vd0 + nb, gvp + 64 + vs0);
      gload16(vd1 + nb, gvp + 64 + vs1);
    }
    f32x4 s0a = (f32x4){0.f, 0.f, 0.f, 0.f}, s0b = (f32x4){0.f, 0.f, 0.f, 0.f};
    f32x4 s1a = (f32x4){0.f, 0.f, 0.f, 0.f}, s1b = (f32x4){0.f, 0.f, 0.f, 0.f};
#pragma unroll
    for (int ks = 0; ks < 4; ++ks) {
      short8 k0f = *(const short8*)(KBp + cb + akr[0][ks]);
      short8 k1f = *(const short8*)(KBp + cb + akr[1][ks]);
      if (ks < 2) { s0a = MFMA16(qf[ks], k0f, s0a); s1a = MFMA16(qf[ks], k1f, s1a); }
      else        { s0b = MFMA16(qf[ks], k0f, s0b); s1b = MFMA16(qf[ks], k1f, s1b); }
    }
#pragma unroll
    for (int r = 0; r < 4; ++r) {
      float p0, p1;
      float sa = s0a[r] + s0b[r];   // logit*log2e (pre-scaled q)
      float sb = s1a[r] + s1b[r];
      asm("v_exp_f32 %0, %1" : "=v"(p0) : "v"(sa));   // 2^x == exp(s)
      asm("v_exp_f32 %0, %1" : "=v"(p1) : "v"(sb));
      Z[r] += p0 + p1;
      unsigned int u;
      asm("v_cvt_pk_bf16_f32 %0, %1, %2" : "=v"(u) : "v"(p0), "v"(p1));
      *(unsigned int*)(pwr + r * 80) = u;   // cols 2lr, 2lr+1 (kv-interleaved)
    }
    // same-wave P write -> read: compiler-ordered via lgkmcnt (no barrier needed)
    short8 pa = *(const short8*)prd;
#pragma unroll
    for (int df = 0; df < 8; ++df) {
      short8 vf = *(const short8*)(VBp + cb + df * 1024 + av0);
      o[df] = MFMA16(pa, vf, o[df]);
    }
    __syncthreads();   // drains vmcnt: staged kt+1 visible; orders reads before next stage
    gkp += 8192; gvp += 64;
  }

  float invZ[4];
#pragma unroll
  for (int r = 0; r < 4; ++r) {
    Z[r] += __shfl_xor(Z[r], 1); Z[r] += __shfl_xor(Z[r], 2);
    Z[r] += __shfl_xor(Z[r], 4); Z[r] += __shfl_xor(Z[r], 8);
    invZ[r] = 1.0f / Z[r];
  }

  const int b = bh / HDS, h = bh % HDS;
#pragma unroll
  for (int df = 0; df < 8; ++df)
#pragma unroll
    for (int r = 0; r < 4; ++r) {
      int l = q0 + lg * 4 + r;
      size_t row = (l < LV) ? ((size_t)b * LV + l) : ((size_t)MV + b * LT + (l - LV));
      int col = h * DD + df * 16 + lr;
      aohi[row * DIMK + col] = f2bf(o[df][r] * invZ[r]);
    }
}

// ---------------- pure-bf16 mainloop, BM=128, dbuf single-barrier (for gemm_out) ----------------
__device__ __forceinline__ void bf16_mainloop128(
    const unsigned short* __restrict__ Ahi, const unsigned short* __restrict__ Bhi,
    int m0, int n0,
    uint4v* __restrict__ sA, uint4v* __restrict__ sB,
    f32x4 (&acc)[4][4]) {
  const int t = threadIdx.x;
  const int lane = t & 63;
  const int w = t >> 6;
  const int wm = w >> 1, wn = w & 1;
  const int lr = lane & 15, lg = lane >> 4;
  const int sr = t >> 1;
  const int sc = (t & 1) * 2;
  const size_t arow = (size_t)(m0 + sr) * DIMK + sc * 8;
  const size_t brow = (size_t)(n0 + sr) * DIMK + sc * 8;
  const int slot0 = sc * 128 + sr, slot1 = (sc + 1) * 128 + sr;
  const int fA = lg * 128 + wm * 64 + lr;
  const int fB = lg * 128 + wn * 64 + lr;

  uint4v va0 = *(const uint4v*)(Ahi + arow);
  uint4v va1 = *(const uint4v*)(Ahi + arow + 8);
  uint4v vb0 = *(const uint4v*)(Bhi + brow);
  uint4v vb1 = *(const uint4v*)(Bhi + brow + 8);

  int cur = 0;
  for (int k0 = 0; k0 < DIMK; k0 += 32) {
    const int hs = cur * 512;
    sA[hs + slot0] = va0; sA[hs + slot1] = va1;
    sB[hs + slot0] = vb0; sB[hs + slot1] = vb1;
    if (k0 + 32 < DIMK) {
      va0 = *(const uint4v*)(Ahi + arow + k0 + 32);
      va1 = *(const uint4v*)(Ahi + arow + k0 + 40);
      vb0 = *(const uint4v*)(Bhi + brow + k0 + 32);
      vb1 = *(const uint4v*)(Bhi + brow + k0 + 40);
    }
    __syncthreads();
    short8 ah[4], bh[4];
#pragma unroll
    for (int i = 0; i < 4; ++i) {
      ah[i] = *(const short8*)&sA[hs + fA + i * 16];
      bh[i] = *(const short8*)&sB[hs + fB + i * 16];
    }
#pragma unroll
    for (int mi = 0; mi < 4; ++mi)
#pragma unroll
      for (int ni = 0; ni < 4; ++ni)
        acc[mi][ni] = MFMA16(ah[mi], bh[ni], acc[mi][ni]);
    cur ^= 1;
  }
}

// ---------------- fused output GEMM (vid+txt) + bias -> f32 d_out ----------------
__global__ __launch_bounds__(256) void gemm_out(
    const unsigned short* __restrict__ Ahi,
    const unsigned short* __restrict__ WvH, const unsigned short* __restrict__ WtH,
    const float* __restrict__ bias_v, const float* __restrict__ bias_t,
    float* __restrict__ out) {
  __shared__ uint4v sA[1024], sB[1024];   // 32KB (dbuf)
  const int t = threadIdx.x;
  const int lane = t & 63;
  const int w = t >> 6;
  const int wm = w >> 1, wn = w & 1;
  const int lr = lane & 15, lg = lane >> 4;
  // XCD decode: bid in [0,384), 48 per XCD, M-chunk of 4 tiles per XCD
  const int bid = blockIdx.x;
  const int xcd = bid & 7, ii = bid >> 3;          // ii in [0,48)
  const int mt = xcd * 4 + (ii & 3), nt = ii >> 2; // mt in [0,32), nt in [0,12)
  const int m0 = mt * 128, n0 = nt * 128;
  const bool istxt = (m0 >= MV);
  const unsigned short* WThi = istxt ? WtH : WvH;
  const float* bias = istxt ? bias_t : bias_v;

  f32x4 acc[4][4];
#pragma unroll
  for (int mi = 0; mi < 4; ++mi)
#pragma unroll
    for (int ni = 0; ni < 4; ++ni) acc[mi][ni] = (f32x4){0.f, 0.f, 0.f, 0.f};

  bf16_mainloop128(Ahi, WThi, m0, n0, sA, sB, acc);

#pragma unroll
  for (int ni = 0; ni < 4; ++ni) {
    float bv = bias[n0 + wn * 64 + ni * 16 + lr];
#pragma unroll
    for (int mi = 0; mi < 4; ++mi)
#pragma unroll
      for (int r = 0; r < 4; ++r) {
        size_t row = (size_t)(m0 + wm * 64 + mi * 16 + lg * 4 + r);
        out[row * DIMK + n0 + wn * 64 + ni * 16 + lr] = acc[mi][ni][r] + bv;
      }
  }
}

// ---------------- launcher ----------------
extern "C" void kernel_launch(void* const* d_in, const int* in_sizes, int n_in,
                              void* d_out, int out_size, void* d_ws, size_t ws_size,
                              hipStream_t stream) {
  (void)in_sizes; (void)n_in; (void)out_size; (void)ws_size;
  const float* vid      = (const float*)d_in[0];
  const float* txt      = (const float*)d_in[1];
  const float* Wqkv_vid = (const float*)d_in[2];
  const float* bqkv_vid = (const float*)d_in[3];
  const float* Wqkv_txt = (const float*)d_in[4];
  const float* bqkv_txt = (const float*)d_in[5];
  const float* nq_vid   = (const float*)d_in[6];
  const float* nk_vid   = (const float*)d_in[7];
  const float* nq_txt   = (const float*)d_in[8];
  const float* nk_txt   = (const float*)d_in[9];
  const float* Wout_vid = (const float*)d_in[10];
  const float* bout_vid = (const float*)d_in[11];
  const float* Wout_txt = (const float*)d_in[12];
  const float* bout_txt = (const float*)d_in[13];
  float* out = (float*)d_out;

  char* ws = (char*)d_ws;
  size_t off = 0;
  auto alloc = [&](size_t bytes) { char* p = ws + off; off += (bytes + 255) & ~(size_t)255; return p; };

  const size_t SZ_X    = (size_t)MTOT * DIMK * 2;   // bf16 bytes
  const size_t SZ_WQKV = (size_t)NIN * DIMK * 2;
  const size_t SZ_WOUT = (size_t)DIMK * DIMK * 2;
  const size_t SZ_QKVB = (size_t)BB * HDS * LL * DD * 2;

  unsigned short* Xhi   = (unsigned short*)alloc(SZ_X);
  unsigned short* WTqvH = (unsigned short*)alloc(SZ_WQKV);
  unsigned short* WTqtH = (unsigned short*)alloc(SZ_WQKV);
  unsigned short* WTovH = (unsigned short*)alloc(SZ_WOUT);
  unsigned short* WTotH = (unsigned short*)alloc(SZ_WOUT);
  unsigned short* QB    = (unsigned short*)alloc(SZ_QKVB);
  unsigned short* KB    = (unsigned short*)alloc(SZ_QKVB);
  unsigned short* VB    = (unsigned short*)alloc(SZ_QKVB);
  unsigned short* VT    = WTqvH;   // reuse: WTqv dead after QKV GEMM (14.2MB >= 12.6MB)
  unsigned short* AOhi  = Xhi;     // reuse: X dead after QKV GEMM

  split_x<<<dim3((MTOT * DIMK) / (256 * 4)), dim3(256), 0, stream>>>(vid, txt, Xhi);
  transpose_cast2<<<dim3(NIN / 32, DIMK / 32, 2), dim3(256), 0, stream>>>(
      Wqkv_vid, WTqvH, Wqkv_txt, WTqtH, DIMK, NIN);
  transpose_cast2<<<dim3(DIMK / 32, DIMK / 32, 2), dim3(256), 0, stream>>>(
      Wout_vid, WTovH, Wout_txt, WTotH, DIMK, DIMK);
  gemm_qkv<<<dim3(576), dim3(512), 0, stream>>>(
      Xhi, WTqvH, WTqtH, bqkv_vid, bqkv_txt,
      nq_vid, nk_vid, nq_txt, nk_txt, QB, KB, VB);
  vt_transpose<<<dim3(LL / 32, DD / 32, BB * HDS), dim3(256), 0, stream>>>(VB, VT);
  attn_kernel<<<dim3(768), dim3(256), 0, stream>>>(QB, KB, VT, AOhi);
  gemm_out<<<dim3(384), dim3(256), 0, stream>>>(
      AOhi, WTovH, WTotH, bout_vid, bout_txt, out);
}